// Round 2
// baseline (391.378 us; speedup 1.0000x reference)
//
#include <hip/hip_runtime.h>
#include <stdint.h>

typedef _Float16 f16x8 __attribute__((ext_vector_type(8)));
typedef float floatx4 __attribute__((ext_vector_type(4)));

#define RR 147456   // 384*384 rows
#define NC 128      // channels
#define NN 384

__device__ inline floatx4 zero4() { floatx4 v; v[0]=0.f; v[1]=0.f; v[2]=0.f; v[3]=0.f; return v; }
__device__ inline float sigmoidf_(float x) { return 1.f / (1.f + __expf(-x)); }

// ---------------------------------------------------------------------------
// k0: repack six fp32 128x128 weights into fp16 FRAGMENT-MAJOR order:
//   wf[slot][ ((k0*8 + nt)*64 + lane)*8 + j ] = W[k][n]
//   where k = k0*32 + (lane>>4)*8 + j,  n = nt*16 + (lane&15)
// so a lane's MFMA B-operand for (k0,nt) is ONE coalesced 16B load at
//   wf + slot*16384 + (k0*8+nt)*512 + lane*8.
// slots: 0=Wa 1=Wga 2=Wb 3=Wgb 4=Wg 5=Wo. Tiny; L2-resident afterwards.
// ---------------------------------------------------------------------------
__global__ __launch_bounds__(256) void k0_wt(
    const float* __restrict__ w0, const float* __restrict__ w1,
    const float* __restrict__ w2, const float* __restrict__ w3,
    const float* __restrict__ w4, const float* __restrict__ w5,
    _Float16* __restrict__ wf)
{
  const float* w;
  switch (blockIdx.x) {
    case 0: w = w0; break; case 1: w = w1; break; case 2: w = w2; break;
    case 3: w = w3; break; case 4: w = w4; break; default: w = w5; break;
  }
  _Float16* out = wf + blockIdx.x * 16384;
  const int t = threadIdx.x;
  for (int it = 0; it < 64; ++it) {
    int f = it * 256 + t;
    int j  = f & 7;
    int ln = (f >> 3) & 63;
    int nt = (f >> 9) & 7;
    int k0 = f >> 12;
    int k = k0 * 32 + (ln >> 4) * 8 + j;
    int n = nt * 16 + (ln & 15);
    out[f] = (_Float16)w[k * 128 + n];
  }
}

// ---------------------------------------------------------------------------
// k2: per 64-row tile: LN1 (16-lane-group reduce, fp32 stats) -> zn fp16 LDS
//     -> A-fragments to registers (ONCE) -> 5 GEMMs with B-operands streamed
//     straight from L2 (fragment-major wf). ONE barrier total.
//   a_t[c][row] = (zn@Wa+ba)*sig(zn@Wga+bga)   (channel-major fp16)
//   b_t[c][row] = (zn@Wb+bb)*sig(zn@Wgb+bgb)
//   gate_t[c][row] = sig(zn@Wg+bg)             (channel-major fp16)
// ---------------------------------------------------------------------------
__global__ __launch_bounds__(256) void k2_ln_gemm(
    const float* __restrict__ z, const float* __restrict__ ln1g, const float* __restrict__ ln1b,
    const _Float16* __restrict__ wf,
    const float* __restrict__ ba, const float* __restrict__ bga,
    const float* __restrict__ bb, const float* __restrict__ bgb,
    const float* __restrict__ bg,
    _Float16* __restrict__ at, _Float16* __restrict__ bt, _Float16* __restrict__ gate)
{
  __shared__ __align__(16) _Float16 zns[64][136];   // zn tile, padded stride
  const int t = threadIdx.x;
  const int w = t >> 6, lane = t & 63;
  const int l15 = lane & 15, quad = lane >> 4;
  const int r0 = blockIdx.x * 64;

  // ---- LN1: wave w owns rows w*16..w*16+15.
  // lane -> (row sub g = lane>>4, channel-group h = lane&15, channels h*8..h*8+7)
  {
    const int g = lane >> 4, h = lane & 15;
    float4 ga = *(const float4*)(ln1g + h*8);
    float4 gb = *(const float4*)(ln1g + h*8 + 4);
    float4 bba = *(const float4*)(ln1b + h*8);
    float4 bbb = *(const float4*)(ln1b + h*8 + 4);
    #pragma unroll
    for (int rr = 0; rr < 4; ++rr) {
      int row = w * 16 + rr * 4 + g;
      const float* zp = z + (size_t)(r0 + row) * NC + h * 8;
      float4 xa = *(const float4*)zp;
      float4 xb = *(const float4*)(zp + 4);
      float s = xa.x + xa.y + xa.z + xa.w + xb.x + xb.y + xb.z + xb.w;
      float q = xa.x*xa.x + xa.y*xa.y + xa.z*xa.z + xa.w*xa.w
              + xb.x*xb.x + xb.y*xb.y + xb.z*xb.z + xb.w*xb.w;
      #pragma unroll
      for (int m = 1; m < 16; m <<= 1) { s += __shfl_xor(s, m); q += __shfl_xor(q, m); }
      float mean = s * (1.f/128.f);
      float var  = q * (1.f/128.f) - mean*mean;
      float rs = rsqrtf(var + 1e-5f);
      union { uint4 u; _Float16 hh[8]; } pk;
      pk.hh[0] = (_Float16)((xa.x - mean) * rs * ga.x + bba.x);
      pk.hh[1] = (_Float16)((xa.y - mean) * rs * ga.y + bba.y);
      pk.hh[2] = (_Float16)((xa.z - mean) * rs * ga.z + bba.z);
      pk.hh[3] = (_Float16)((xa.w - mean) * rs * ga.w + bba.w);
      pk.hh[4] = (_Float16)((xb.x - mean) * rs * gb.x + bbb.x);
      pk.hh[5] = (_Float16)((xb.y - mean) * rs * gb.y + bbb.y);
      pk.hh[6] = (_Float16)((xb.z - mean) * rs * gb.z + bbb.z);
      pk.hh[7] = (_Float16)((xb.w - mean) * rs * gb.w + bbb.w);
      *(uint4*)&zns[row][h * 8] = pk.u;
    }
  }
  __syncthreads();

  // A-fragments once, reused by all 5 GEMMs
  f16x8 af[4];
  #pragma unroll
  for (int k0 = 0; k0 < 4; ++k0)
    af[k0] = *(const f16x8*)&zns[w*16 + l15][k0*32 + quad*8];

  auto gemm = [&](int slot, floatx4* acc) {
    const _Float16* p = wf + slot * 16384 + lane * 8;
    #pragma unroll
    for (int nt = 0; nt < 8; ++nt) acc[nt] = zero4();
    #pragma unroll
    for (int k0 = 0; k0 < 4; ++k0) {
      #pragma unroll
      for (int nt = 0; nt < 8; ++nt) {
        f16x8 bfr = *(const f16x8*)(p + (k0*8 + nt) * 512);
        acc[nt] = __builtin_amdgcn_mfma_f32_16x16x32_f16(af[k0], bfr, acc[nt], 0, 0, 0);
      }
    }
  };
  auto combine_store = [&](const floatx4* aP, const floatx4* aG,
                           const float* bia, const float* big, _Float16* dst) {
    #pragma unroll
    for (int nt = 0; nt < 8; ++nt) {
      int c = nt*16 + l15;
      float bav = bia[c], bgv = big[c];
      union { uint2 u2; _Float16 h[4]; } pk;
      #pragma unroll
      for (int r = 0; r < 4; ++r) {
        float p  = aP[nt][r] + bav;
        float gg = aG[nt][r] + bgv;
        pk.h[r] = (_Float16)(p * sigmoidf_(gg));
      }
      *(uint2*)(dst + (size_t)c * RR + r0 + w*16 + quad*4) = pk.u2;
    }
  };

  floatx4 accP[8], accG[8];

  gemm(0, accP); gemm(1, accG); combine_store(accP, accG, ba, bga, at);
  gemm(2, accP); gemm(3, accG); combine_store(accP, accG, bb, bgb, bt);
  gemm(4, accG);
  // gate: channel-major store, same pattern as at/bt
  #pragma unroll
  for (int nt = 0; nt < 8; ++nt) {
    int c = nt*16 + l15;
    float bgv = bg[c];
    union { uint2 u2; _Float16 h[4]; } pk;
    #pragma unroll
    for (int r = 0; r < 4; ++r)
      pk.h[r] = (_Float16)sigmoidf_(accG[nt][r] + bgv);
    *(uint2*)(gate + (size_t)c * RR + r0 + w*16 + quad*4) = pk.u2;
  }
}

// ---------------------------------------------------------------------------
// k3: triangle einsum. Per channel c: o_t[c] = A_c(384x384) @ B_c^T.
// grid (9 tiles, 128 channels); block computes 128x128 o-tile, wave = 64x64.
// (unchanged this round)
// ---------------------------------------------------------------------------
__global__ __launch_bounds__(256) void k3_tri(
    const _Float16* __restrict__ at, const _Float16* __restrict__ bt, float* __restrict__ o)
{
  __shared__ __align__(16) _Float16 As[128][72];
  __shared__ __align__(16) _Float16 Bs[128][72];
  const int t = threadIdx.x;
  const int w = t >> 6, lane = t & 63, l15 = lane & 15, quad = lane >> 4;
  const int c = blockIdx.y;
  const int i0 = (blockIdx.x / 3) * 128, j0 = (blockIdx.x % 3) * 128;
  const int wi = w >> 1, wj = w & 1;
  const size_t base = (size_t)c * RR;
  const _Float16* A  = at + base;
  const _Float16* Bp = bt + base;

  floatx4 acc[4][4];
  #pragma unroll
  for (int mt = 0; mt < 4; ++mt)
    #pragma unroll
    for (int nt = 0; nt < 4; ++nt) acc[mt][nt] = zero4();

  for (int kk = 0; kk < NN; kk += 64) {
    #pragma unroll
    for (int s2 = 0; s2 < 4; ++s2) {
      int f = s2 * 2048 + t * 8;        // contiguous across lanes
      int row = f >> 6, k = f & 63;
      *(uint4*)&As[row][k] = *(const uint4*)(A  + (size_t)(i0 + row) * NN + kk + k);
      *(uint4*)&Bs[row][k] = *(const uint4*)(Bp + (size_t)(j0 + row) * NN + kk + k);
    }
    __syncthreads();
    #pragma unroll
    for (int k0 = 0; k0 < 64; k0 += 32) {
      f16x8 af[4], bfr[4];
      #pragma unroll
      for (int mt = 0; mt < 4; ++mt) af[mt]  = *(const f16x8*)&As[wi*64 + mt*16 + l15][k0 + quad*8];
      #pragma unroll
      for (int nt = 0; nt < 4; ++nt) bfr[nt] = *(const f16x8*)&Bs[wj*64 + nt*16 + l15][k0 + quad*8];
      #pragma unroll
      for (int mt = 0; mt < 4; ++mt)
        #pragma unroll
        for (int nt = 0; nt < 4; ++nt)
          acc[mt][nt] = __builtin_amdgcn_mfma_f32_16x16x32_f16(af[mt], bfr[nt], acc[mt][nt], 0, 0, 0);
    }
    __syncthreads();
  }
  // store fp32, 64B-contiguous per (quad,reg) row
  #pragma unroll
  for (int mt = 0; mt < 4; ++mt) {
    #pragma unroll
    for (int r = 0; r < 4; ++r) {
      int i = i0 + wi*64 + mt*16 + quad*4 + r;
      float* orow = o + base + (size_t)i * NN + j0 + wj*64;
      #pragma unroll
      for (int nt = 0; nt < 4; ++nt) orow[nt*16 + l15] = acc[mt][nt][r];
    }
  }
}

// ---------------------------------------------------------------------------
// k4: per 64-position tile: gather o (channel-major fp32) -> LDS transpose ->
//     LN2 (16-lane-group) -> MFMA with Wo streamed from L2 -> *gate -> fp32 out
// ---------------------------------------------------------------------------
__global__ __launch_bounds__(256) void k4_out(
    const float* __restrict__ o, const _Float16* __restrict__ gate,
    const float* __restrict__ ln2g, const float* __restrict__ ln2b,
    const _Float16* __restrict__ wo5, const float* __restrict__ bo,
    float* __restrict__ out)
{
  __shared__ __align__(16) float    osb[64][132];   // o tile [pos][c]; stride 132 -> 16B-aligned rows
  __shared__ __align__(16) _Float16 ans[64][136];   // normalized tile (fp16)
  const int t = threadIdx.x;
  const int w = t >> 6, lane = t & 63, l15 = lane & 15, quad = lane >> 4;
  const int r0 = blockIdx.x * 64;

  // gather o: 16B-contiguous per channel plane, transpose into [pos][c]
  #pragma unroll
  for (int it = 0; it < 8; ++it) {
    int f = it * 1024 + t * 4;
    int cx = f >> 6, p = f & 63;
    float4 v = *(const float4*)(o + (size_t)cx * RR + r0 + p);
    osb[p+0][cx] = v.x; osb[p+1][cx] = v.y; osb[p+2][cx] = v.z; osb[p+3][cx] = v.w;
  }
  __syncthreads();

  // LN2: 16-lane-group reduce, fp32 stats
  {
    const int g = lane >> 4, h = lane & 15;
    float4 ga = *(const float4*)(ln2g + h*8);
    float4 gb = *(const float4*)(ln2g + h*8 + 4);
    float4 bba = *(const float4*)(ln2b + h*8);
    float4 bbb = *(const float4*)(ln2b + h*8 + 4);
    #pragma unroll
    for (int rr = 0; rr < 4; ++rr) {
      int row = w * 16 + rr * 4 + g;
      float4 xa = *(const float4*)&osb[row][h*8];
      float4 xb = *(const float4*)&osb[row][h*8 + 4];
      float s = xa.x + xa.y + xa.z + xa.w + xb.x + xb.y + xb.z + xb.w;
      float q = xa.x*xa.x + xa.y*xa.y + xa.z*xa.z + xa.w*xa.w
              + xb.x*xb.x + xb.y*xb.y + xb.z*xb.z + xb.w*xb.w;
      #pragma unroll
      for (int m = 1; m < 16; m <<= 1) { s += __shfl_xor(s, m); q += __shfl_xor(q, m); }
      float mean = s * (1.f/128.f);
      float var  = q * (1.f/128.f) - mean*mean;
      float rs = rsqrtf(var + 1e-5f);
      union { uint4 u; _Float16 hh[8]; } pk;
      pk.hh[0] = (_Float16)((xa.x - mean) * rs * ga.x + bba.x);
      pk.hh[1] = (_Float16)((xa.y - mean) * rs * ga.y + bba.y);
      pk.hh[2] = (_Float16)((xa.z - mean) * rs * ga.z + bba.z);
      pk.hh[3] = (_Float16)((xa.w - mean) * rs * ga.w + bba.w);
      pk.hh[4] = (_Float16)((xb.x - mean) * rs * gb.x + bbb.x);
      pk.hh[5] = (_Float16)((xb.y - mean) * rs * gb.y + bbb.y);
      pk.hh[6] = (_Float16)((xb.z - mean) * rs * gb.z + bbb.z);
      pk.hh[7] = (_Float16)((xb.w - mean) * rs * gb.w + bbb.w);
      *(uint4*)&ans[row][h * 8] = pk.u;
    }
  }
  __syncthreads();

  f16x8 af[4];
  #pragma unroll
  for (int k0 = 0; k0 < 4; ++k0)
    af[k0] = *(const f16x8*)&ans[w*16 + l15][k0*32 + quad*8];

  floatx4 acc[8];
  #pragma unroll
  for (int nt = 0; nt < 8; ++nt) acc[nt] = zero4();
  {
    const _Float16* p = wo5 + lane * 8;
    #pragma unroll
    for (int k0 = 0; k0 < 4; ++k0) {
      #pragma unroll
      for (int nt = 0; nt < 8; ++nt) {
        f16x8 bfr = *(const f16x8*)(p + (k0*8 + nt) * 512);
        acc[nt] = __builtin_amdgcn_mfma_f32_16x16x32_f16(af[k0], bfr, acc[nt], 0, 0, 0);
      }
    }
  }

  // epilogue: out = gate * (acc + bo); gate is channel-major fp16, 8B loads
  #pragma unroll
  for (int nt = 0; nt < 8; ++nt) {
    int c = nt*16 + l15;
    float bov = bo[c];
    union { uint2 u2; _Float16 h[4]; } gk;
    gk.u2 = *(const uint2*)(gate + (size_t)c * RR + r0 + w*16 + quad*4);
    #pragma unroll
    for (int r = 0; r < 4; ++r) {
      int rl = w*16 + quad*4 + r;
      out[(size_t)(r0 + rl) * NC + c] = (float)gk.h[r] * (acc[nt][r] + bov);
    }
  }
}

// ---------------------------------------------------------------------------
// Workspace layout (bytes):
//   a_t   @ 0          : 147456*128*2 = 37748736   (fp16, channel-major)
//   b_t   @ 37748736   : 37748736
//   gate  @ 75497472   : 37748736                  (fp16, channel-major)
//   o     @ 113246208  : 147456*128*4 = 75497472   (fp32, channel-major)
//   wf    @ 188743680  : 6*16384*2 = 196608        (fragment-major fp16 weights)
//   total 188940288
// ---------------------------------------------------------------------------
extern "C" void kernel_launch(void* const* d_in, const int* in_sizes, int n_in,
                              void* d_out, int out_size, void* d_ws, size_t ws_size,
                              hipStream_t stream) {
  const float* z    = (const float*)d_in[0];
  const float* l1g  = (const float*)d_in[1];
  const float* l1b  = (const float*)d_in[2];
  const float* l2g  = (const float*)d_in[3];
  const float* l2b  = (const float*)d_in[4];
  const float* Wa   = (const float*)d_in[5];
  const float* ba   = (const float*)d_in[6];
  const float* Wga  = (const float*)d_in[7];
  const float* bga  = (const float*)d_in[8];
  const float* Wb   = (const float*)d_in[9];
  const float* bb   = (const float*)d_in[10];
  const float* Wgb  = (const float*)d_in[11];
  const float* bgb  = (const float*)d_in[12];
  const float* Wg   = (const float*)d_in[13];
  const float* bg   = (const float*)d_in[14];
  const float* Wo   = (const float*)d_in[15];
  const float* bo   = (const float*)d_in[16];

  char* ws = (char*)d_ws;
  _Float16* at_  = (_Float16*)(ws + 0);
  _Float16* bt_  = (_Float16*)(ws + 37748736);
  _Float16* gate = (_Float16*)(ws + 75497472);
  float*    o    = (float*)   (ws + 113246208);
  _Float16* wf   = (_Float16*)(ws + 188743680);

  hipLaunchKernelGGL(k0_wt, dim3(6), dim3(256), 0, stream, Wa, Wga, Wb, Wgb, Wg, Wo, wf);
  hipLaunchKernelGGL(k2_ln_gemm, dim3(2304), dim3(256), 0, stream,
                     z, l1g, l1b, wf, ba, bga, bb, bgb, bg, at_, bt_, gate);
  hipLaunchKernelGGL(k3_tri, dim3(9, 128), dim3(256), 0, stream, at_, bt_, o);
  hipLaunchKernelGGL(k4_out, dim3(2304), dim3(256), 0, stream,
                     o, gate, l2g, l2b, wf + 5*16384, bo, (float*)d_out);
}

// Round 3
// 329.151 us; speedup vs baseline: 1.1891x; 1.1891x over previous
//
#include <hip/hip_runtime.h>
#include <stdint.h>

typedef _Float16 f16x8 __attribute__((ext_vector_type(8)));
typedef float floatx4 __attribute__((ext_vector_type(4)));

#define RR 147456   // 384*384 rows
#define NC 128      // channels
#define NN 384

__device__ inline floatx4 zero4() { floatx4 v; v[0]=0.f; v[1]=0.f; v[2]=0.f; v[3]=0.f; return v; }
__device__ inline float sigmoidf_(float x) { return 1.f / (1.f + __expf(-x)); }

// ---------------------------------------------------------------------------
// k0: repack six fp32 128x128 weights into fp16 FRAGMENT-MAJOR order:
//   wf[slot][ ((k0*8 + nt)*64 + lane)*8 + j ] = W[k][n]
//   where k = k0*32 + (lane>>4)*8 + j,  n = nt*16 + (lane&15)
// A lane's MFMA B-operand for (k0,nt) is ONE coalesced 16B load.
// slots: 0=Wa 1=Wga 2=Wb 3=Wgb 4=Wg 5=Wo. L2-resident afterwards.
// ---------------------------------------------------------------------------
__global__ __launch_bounds__(256) void k0_wt(
    const float* __restrict__ w0, const float* __restrict__ w1,
    const float* __restrict__ w2, const float* __restrict__ w3,
    const float* __restrict__ w4, const float* __restrict__ w5,
    _Float16* __restrict__ wf)
{
  const float* w;
  switch (blockIdx.x) {
    case 0: w = w0; break; case 1: w = w1; break; case 2: w = w2; break;
    case 3: w = w3; break; case 4: w = w4; break; default: w = w5; break;
  }
  _Float16* out = wf + blockIdx.x * 16384;
  const int t = threadIdx.x;
  for (int it = 0; it < 64; ++it) {
    int f = it * 256 + t;
    int j  = f & 7;
    int ln = (f >> 3) & 63;
    int nt = (f >> 9) & 7;
    int k0 = f >> 12;
    int k = k0 * 32 + (ln >> 4) * 8 + j;
    int n = nt * 16 + (ln & 15);
    out[f] = (_Float16)w[k * 128 + n];
  }
}

// ---------------------------------------------------------------------------
// k2: per 64-row tile: LN1 (16-lane-group reduce) -> zn fp16 in LDS -> ONE
// barrier -> A-fragments for ALL 64 rows cached in 16 VGPR-quads -> 5 GEMMs.
// N-SPLIT: wave w owns channel-tiles {2w, 2w+1}; per-GEMM weight loads are
// 8x16B per lane (block reads each weight exactly once). Weights double-
// buffered in registers so next slot's loads hide under current MFMAs.
// ---------------------------------------------------------------------------
__global__ __launch_bounds__(256) void k2_ln_gemm(
    const float* __restrict__ z, const float* __restrict__ ln1g, const float* __restrict__ ln1b,
    const _Float16* __restrict__ wf,
    const float* __restrict__ ba, const float* __restrict__ bga,
    const float* __restrict__ bb, const float* __restrict__ bgb,
    const float* __restrict__ bg,
    _Float16* __restrict__ at, _Float16* __restrict__ bt, _Float16* __restrict__ gate)
{
  __shared__ __align__(16) _Float16 zns[64][136];   // zn tile, padded stride
  const int t = threadIdx.x;
  const int w = t >> 6, lane = t & 63;
  const int l15 = lane & 15, quad = lane >> 4;
  const int r0 = blockIdx.x * 64;
  const int nt0 = w * 2;            // this wave's channel-tile pair

  // ---- LN1: wave w owns rows w*16..w*16+15.
  {
    const int g = lane >> 4, h = lane & 15;
    float4 ga = *(const float4*)(ln1g + h*8);
    float4 gb = *(const float4*)(ln1g + h*8 + 4);
    float4 bba = *(const float4*)(ln1b + h*8);
    float4 bbb = *(const float4*)(ln1b + h*8 + 4);
    #pragma unroll
    for (int rr = 0; rr < 4; ++rr) {
      int row = w * 16 + rr * 4 + g;
      const float* zp = z + (size_t)(r0 + row) * NC + h * 8;
      float4 xa = *(const float4*)zp;
      float4 xb = *(const float4*)(zp + 4);
      float s = xa.x + xa.y + xa.z + xa.w + xb.x + xb.y + xb.z + xb.w;
      float q = xa.x*xa.x + xa.y*xa.y + xa.z*xa.z + xa.w*xa.w
              + xb.x*xb.x + xb.y*xb.y + xb.z*xb.z + xb.w*xb.w;
      #pragma unroll
      for (int m = 1; m < 16; m <<= 1) { s += __shfl_xor(s, m); q += __shfl_xor(q, m); }
      float mean = s * (1.f/128.f);
      float var  = q * (1.f/128.f) - mean*mean;
      float rs = rsqrtf(var + 1e-5f);
      union { uint4 u; _Float16 hh[8]; } pk;
      pk.hh[0] = (_Float16)((xa.x - mean) * rs * ga.x + bba.x);
      pk.hh[1] = (_Float16)((xa.y - mean) * rs * ga.y + bba.y);
      pk.hh[2] = (_Float16)((xa.z - mean) * rs * ga.z + bba.z);
      pk.hh[3] = (_Float16)((xa.w - mean) * rs * ga.w + bba.w);
      pk.hh[4] = (_Float16)((xb.x - mean) * rs * gb.x + bbb.x);
      pk.hh[5] = (_Float16)((xb.y - mean) * rs * gb.y + bbb.y);
      pk.hh[6] = (_Float16)((xb.z - mean) * rs * gb.z + bbb.z);
      pk.hh[7] = (_Float16)((xb.w - mean) * rs * gb.w + bbb.w);
      *(uint4*)&zns[row][h * 8] = pk.u;
    }
  }
  __syncthreads();

  // A-fragments for all 64 rows, loaded once, reused by all 5 GEMMs.
  f16x8 af[4][4];   // [mt][k0]
  #pragma unroll
  for (int mt = 0; mt < 4; ++mt)
    #pragma unroll
    for (int k0 = 0; k0 < 4; ++k0)
      af[mt][k0] = *(const f16x8*)&zns[mt*16 + l15][k0*32 + quad*8];

  const _Float16* pw = wf + lane * 8;
  auto loadw = [&](f16x8 (&bw)[4][2], int slot) {
    const _Float16* p = pw + slot * 16384;
    #pragma unroll
    for (int k0 = 0; k0 < 4; ++k0)
      #pragma unroll
      for (int j = 0; j < 2; ++j)
        bw[k0][j] = *(const f16x8*)(p + (k0*8 + nt0 + j) * 512);
  };
  auto dogemm = [&](const f16x8 (&bw)[4][2], floatx4 (&acc)[4][2]) {
    #pragma unroll
    for (int mt = 0; mt < 4; ++mt)
      #pragma unroll
      for (int j = 0; j < 2; ++j)
        acc[mt][j] = zero4();
    #pragma unroll
    for (int k0 = 0; k0 < 4; ++k0)
      #pragma unroll
      for (int mt = 0; mt < 4; ++mt) {
        acc[mt][0] = __builtin_amdgcn_mfma_f32_16x16x32_f16(af[mt][k0], bw[k0][0], acc[mt][0], 0, 0, 0);
        acc[mt][1] = __builtin_amdgcn_mfma_f32_16x16x32_f16(af[mt][k0], bw[k0][1], acc[mt][1], 0, 0, 0);
      }
  };
  auto combine_store = [&](const floatx4 (&aP)[4][2], const floatx4 (&aG)[4][2],
                           const float* bia, const float* big, _Float16* dst) {
    #pragma unroll
    for (int j = 0; j < 2; ++j) {
      int c = (nt0 + j)*16 + l15;
      float bav = bia[c], bgv = big[c];
      #pragma unroll
      for (int mt = 0; mt < 4; ++mt) {
        union { uint2 u2; _Float16 h[4]; } pk;
        #pragma unroll
        for (int r = 0; r < 4; ++r) {
          float p  = aP[mt][j][r] + bav;
          float gg = aG[mt][j][r] + bgv;
          pk.h[r] = (_Float16)(p * sigmoidf_(gg));
        }
        *(uint2*)(dst + (size_t)c * RR + r0 + mt*16 + quad*4) = pk.u2;
      }
    }
  };

  f16x8 bwA[4][2], bwB[4][2];
  floatx4 accP[4][2], accG[4][2];

  loadw(bwA, 0);                       // Wa
  loadw(bwB, 1);                       // Wga
  dogemm(bwA, accP);                   // slot 0
  loadw(bwA, 2);                       // prefetch Wb
  dogemm(bwB, accG);                   // slot 1
  combine_store(accP, accG, ba, bga, at);
  loadw(bwB, 3);                       // prefetch Wgb
  dogemm(bwA, accP);                   // slot 2
  loadw(bwA, 4);                       // prefetch Wg
  dogemm(bwB, accG);                   // slot 3
  combine_store(accP, accG, bb, bgb, bt);
  dogemm(bwA, accG);                   // slot 4 (Wg)

  // gate: channel-major store
  #pragma unroll
  for (int j = 0; j < 2; ++j) {
    int c = (nt0 + j)*16 + l15;
    float bgv = bg[c];
    #pragma unroll
    for (int mt = 0; mt < 4; ++mt) {
      union { uint2 u2; _Float16 h[4]; } pk;
      #pragma unroll
      for (int r = 0; r < 4; ++r)
        pk.h[r] = (_Float16)sigmoidf_(accG[mt][j][r] + bgv);
      *(uint2*)(gate + (size_t)c * RR + r0 + mt*16 + quad*4) = pk.u2;
    }
  }
}

// ---------------------------------------------------------------------------
// k3: triangle einsum. Per channel c: o_t[c] = A_c(384x384) @ B_c^T.
// grid (9 tiles, 128 channels); block computes 128x128 o-tile, wave = 64x64.
// (unchanged this round)
// ---------------------------------------------------------------------------
__global__ __launch_bounds__(256) void k3_tri(
    const _Float16* __restrict__ at, const _Float16* __restrict__ bt, float* __restrict__ o)
{
  __shared__ __align__(16) _Float16 As[128][72];
  __shared__ __align__(16) _Float16 Bs[128][72];
  const int t = threadIdx.x;
  const int w = t >> 6, lane = t & 63, l15 = lane & 15, quad = lane >> 4;
  const int c = blockIdx.y;
  const int i0 = (blockIdx.x / 3) * 128, j0 = (blockIdx.x % 3) * 128;
  const int wi = w >> 1, wj = w & 1;
  const size_t base = (size_t)c * RR;
  const _Float16* A  = at + base;
  const _Float16* Bp = bt + base;

  floatx4 acc[4][4];
  #pragma unroll
  for (int mt = 0; mt < 4; ++mt)
    #pragma unroll
    for (int nt = 0; nt < 4; ++nt) acc[mt][nt] = zero4();

  for (int kk = 0; kk < NN; kk += 64) {
    #pragma unroll
    for (int s2 = 0; s2 < 4; ++s2) {
      int f = s2 * 2048 + t * 8;        // contiguous across lanes
      int row = f >> 6, k = f & 63;
      *(uint4*)&As[row][k] = *(const uint4*)(A  + (size_t)(i0 + row) * NN + kk + k);
      *(uint4*)&Bs[row][k] = *(const uint4*)(Bp + (size_t)(j0 + row) * NN + kk + k);
    }
    __syncthreads();
    #pragma unroll
    for (int k0 = 0; k0 < 64; k0 += 32) {
      f16x8 af[4], bfr[4];
      #pragma unroll
      for (int mt = 0; mt < 4; ++mt) af[mt]  = *(const f16x8*)&As[wi*64 + mt*16 + l15][k0 + quad*8];
      #pragma unroll
      for (int nt = 0; nt < 4; ++nt) bfr[nt] = *(const f16x8*)&Bs[wj*64 + nt*16 + l15][k0 + quad*8];
      #pragma unroll
      for (int mt = 0; mt < 4; ++mt)
        #pragma unroll
        for (int nt = 0; nt < 4; ++nt)
          acc[mt][nt] = __builtin_amdgcn_mfma_f32_16x16x32_f16(af[mt], bfr[nt], acc[mt][nt], 0, 0, 0);
    }
    __syncthreads();
  }
  // store fp32, 64B-contiguous per (quad,reg) row
  #pragma unroll
  for (int mt = 0; mt < 4; ++mt) {
    #pragma unroll
    for (int r = 0; r < 4; ++r) {
      int i = i0 + wi*64 + mt*16 + quad*4 + r;
      float* orow = o + base + (size_t)i * NN + j0 + wj*64;
      #pragma unroll
      for (int nt = 0; nt < 4; ++nt) orow[nt*16 + l15] = acc[mt][nt][r];
    }
  }
}

// ---------------------------------------------------------------------------
// k4: per 64-position tile: gather o (channel-major fp32) -> LDS transpose ->
//     LN2 (16-lane-group) -> N-split MFMA with Wo from L2 -> *gate -> fp32 out
// ---------------------------------------------------------------------------
__global__ __launch_bounds__(256) void k4_out(
    const float* __restrict__ o, const _Float16* __restrict__ gate,
    const float* __restrict__ ln2g, const float* __restrict__ ln2b,
    const _Float16* __restrict__ wo5, const float* __restrict__ bo,
    float* __restrict__ out)
{
  __shared__ __align__(16) float    osb[64][132];   // o tile [pos][c]; 16B-aligned rows
  __shared__ __align__(16) _Float16 ans[64][136];   // normalized tile (fp16)
  const int t = threadIdx.x;
  const int w = t >> 6, lane = t & 63, l15 = lane & 15, quad = lane >> 4;
  const int r0 = blockIdx.x * 64;
  const int nt0 = w * 2;

  // gather o: 16B-contiguous per channel plane, transpose into [pos][c]
  #pragma unroll
  for (int it = 0; it < 8; ++it) {
    int f = it * 1024 + t * 4;
    int cx = f >> 6, p = f & 63;
    float4 v = *(const float4*)(o + (size_t)cx * RR + r0 + p);
    osb[p+0][cx] = v.x; osb[p+1][cx] = v.y; osb[p+2][cx] = v.z; osb[p+3][cx] = v.w;
  }
  __syncthreads();

  // LN2: 16-lane-group reduce, fp32 stats
  {
    const int g = lane >> 4, h = lane & 15;
    float4 ga = *(const float4*)(ln2g + h*8);
    float4 gb = *(const float4*)(ln2g + h*8 + 4);
    float4 bba = *(const float4*)(ln2b + h*8);
    float4 bbb = *(const float4*)(ln2b + h*8 + 4);
    #pragma unroll
    for (int rr = 0; rr < 4; ++rr) {
      int row = w * 16 + rr * 4 + g;
      float4 xa = *(const float4*)&osb[row][h*8];
      float4 xb = *(const float4*)&osb[row][h*8 + 4];
      float s = xa.x + xa.y + xa.z + xa.w + xb.x + xb.y + xb.z + xb.w;
      float q = xa.x*xa.x + xa.y*xa.y + xa.z*xa.z + xa.w*xa.w
              + xb.x*xb.x + xb.y*xb.y + xb.z*xb.z + xb.w*xb.w;
      #pragma unroll
      for (int m = 1; m < 16; m <<= 1) { s += __shfl_xor(s, m); q += __shfl_xor(q, m); }
      float mean = s * (1.f/128.f);
      float var  = q * (1.f/128.f) - mean*mean;
      float rs = rsqrtf(var + 1e-5f);
      union { uint4 u; _Float16 hh[8]; } pk;
      pk.hh[0] = (_Float16)((xa.x - mean) * rs * ga.x + bba.x);
      pk.hh[1] = (_Float16)((xa.y - mean) * rs * ga.y + bba.y);
      pk.hh[2] = (_Float16)((xa.z - mean) * rs * ga.z + bba.z);
      pk.hh[3] = (_Float16)((xa.w - mean) * rs * ga.w + bba.w);
      pk.hh[4] = (_Float16)((xb.x - mean) * rs * gb.x + bbb.x);
      pk.hh[5] = (_Float16)((xb.y - mean) * rs * gb.y + bbb.y);
      pk.hh[6] = (_Float16)((xb.z - mean) * rs * gb.z + bbb.z);
      pk.hh[7] = (_Float16)((xb.w - mean) * rs * gb.w + bbb.w);
      *(uint4*)&ans[row][h * 8] = pk.u;
    }
  }
  __syncthreads();

  // B-operand loads first (8x16B per lane), then A-fragments, then MFMA
  f16x8 bw[4][2];
  {
    const _Float16* p = wo5 + lane * 8;
    #pragma unroll
    for (int k0 = 0; k0 < 4; ++k0)
      #pragma unroll
      for (int j = 0; j < 2; ++j)
        bw[k0][j] = *(const f16x8*)(p + (k0*8 + nt0 + j) * 512);
  }
  f16x8 af[4][4];
  #pragma unroll
  for (int mt = 0; mt < 4; ++mt)
    #pragma unroll
    for (int k0 = 0; k0 < 4; ++k0)
      af[mt][k0] = *(const f16x8*)&ans[mt*16 + l15][k0*32 + quad*8];

  floatx4 acc[4][2];
  #pragma unroll
  for (int mt = 0; mt < 4; ++mt)
    #pragma unroll
    for (int j = 0; j < 2; ++j) acc[mt][j] = zero4();
  #pragma unroll
  for (int k0 = 0; k0 < 4; ++k0)
    #pragma unroll
    for (int mt = 0; mt < 4; ++mt) {
      acc[mt][0] = __builtin_amdgcn_mfma_f32_16x16x32_f16(af[mt][k0], bw[k0][0], acc[mt][0], 0, 0, 0);
      acc[mt][1] = __builtin_amdgcn_mfma_f32_16x16x32_f16(af[mt][k0], bw[k0][1], acc[mt][1], 0, 0, 0);
    }

  // epilogue: out = gate * (acc + bo); gate channel-major fp16, 8B loads
  #pragma unroll
  for (int j = 0; j < 2; ++j) {
    int c = (nt0 + j)*16 + l15;
    float bov = bo[c];
    #pragma unroll
    for (int mt = 0; mt < 4; ++mt) {
      union { uint2 u2; _Float16 h[4]; } gk;
      gk.u2 = *(const uint2*)(gate + (size_t)c * RR + r0 + mt*16 + quad*4);
      #pragma unroll
      for (int r = 0; r < 4; ++r) {
        int rl = mt*16 + quad*4 + r;
        out[(size_t)(r0 + rl) * NC + c] = (float)gk.h[r] * (acc[mt][j][r] + bov);
      }
    }
  }
}

// ---------------------------------------------------------------------------
// Workspace layout (bytes):
//   a_t   @ 0          : 147456*128*2 = 37748736   (fp16, channel-major)
//   b_t   @ 37748736   : 37748736
//   gate  @ 75497472   : 37748736                  (fp16, channel-major)
//   o     @ 113246208  : 147456*128*4 = 75497472   (fp32, channel-major)
//   wf    @ 188743680  : 6*16384*2 = 196608        (fragment-major fp16 weights)
//   total 188940288
// ---------------------------------------------------------------------------
extern "C" void kernel_launch(void* const* d_in, const int* in_sizes, int n_in,
                              void* d_out, int out_size, void* d_ws, size_t ws_size,
                              hipStream_t stream) {
  const float* z    = (const float*)d_in[0];
  const float* l1g  = (const float*)d_in[1];
  const float* l1b  = (const float*)d_in[2];
  const float* l2g  = (const float*)d_in[3];
  const float* l2b  = (const float*)d_in[4];
  const float* Wa   = (const float*)d_in[5];
  const float* ba   = (const float*)d_in[6];
  const float* Wga  = (const float*)d_in[7];
  const float* bga  = (const float*)d_in[8];
  const float* Wb   = (const float*)d_in[9];
  const float* bb   = (const float*)d_in[10];
  const float* Wgb  = (const float*)d_in[11];
  const float* bgb  = (const float*)d_in[12];
  const float* Wg   = (const float*)d_in[13];
  const float* bg   = (const float*)d_in[14];
  const float* Wo   = (const float*)d_in[15];
  const float* bo   = (const float*)d_in[16];

  char* ws = (char*)d_ws;
  _Float16* at_  = (_Float16*)(ws + 0);
  _Float16* bt_  = (_Float16*)(ws + 37748736);
  _Float16* gate = (_Float16*)(ws + 75497472);
  float*    o    = (float*)   (ws + 113246208);
  _Float16* wf   = (_Float16*)(ws + 188743680);

  hipLaunchKernelGGL(k0_wt, dim3(6), dim3(256), 0, stream, Wa, Wga, Wb, Wgb, Wg, Wo, wf);
  hipLaunchKernelGGL(k2_ln_gemm, dim3(2304), dim3(256), 0, stream,
                     z, l1g, l1b, wf, ba, bga, bb, bgb, bg, at_, bt_, gate);
  hipLaunchKernelGGL(k3_tri, dim3(9, 128), dim3(256), 0, stream, at_, bt_, o);
  hipLaunchKernelGGL(k4_out, dim3(2304), dim3(256), 0, stream,
                     o, gate, l2g, l2b, wf + 5*16384, bo, (float*)d_out);
}